// Round 1
// baseline (815.179 us; speedup 1.0000x reference)
//
#include <hip/hip_runtime.h>

// GAT 2-layer, N=100000, E=1600000 (+N self loops), 128 -> 4x32 -> 4x32
#define NN 100000
#define EE 1600000
#define ET (NN + EE)

__device__ __forceinline__ float leaky(float x) { return x > 0.f ? x : 0.2f * x; }

// ---------------- CSR build ----------------

__global__ __launch_bounds__(256) void hist_kernel(const int* __restrict__ dst, int* __restrict__ cnt)
{
    for (int e = blockIdx.x * 256 + threadIdx.x; e < ET; e += gridDim.x * 256) {
        int d = (e < EE) ? dst[e] : (e - EE);
        atomicAdd(&cnt[d], 1);
    }
}

__global__ __launch_bounds__(1024) void scan_kernel(const int* __restrict__ cnt, int* __restrict__ rowptr)
{
    __shared__ int wsum[16];
    __shared__ int tot;
    const int t = threadIdx.x, lane = t & 63, w = t >> 6;
    int carry = 0;
    for (int base = 0; base < NN; base += 4096) {
        int idx = base + t * 4;
        int v0 = (idx + 0 < NN) ? cnt[idx + 0] : 0;
        int v1 = (idx + 1 < NN) ? cnt[idx + 1] : 0;
        int v2 = (idx + 2 < NN) ? cnt[idx + 2] : 0;
        int v3 = (idx + 3 < NN) ? cnt[idx + 3] : 0;
        int s = v0 + v1 + v2 + v3;
        int sc = s;
        #pragma unroll
        for (int off = 1; off < 64; off <<= 1) {
            int u = __shfl_up(sc, off);
            if (lane >= off) sc += u;
        }
        if (lane == 63) wsum[w] = sc;
        __syncthreads();
        if (t == 0) {
            int a = 0;
            for (int i = 0; i < 16; i++) { int xch = wsum[i]; wsum[i] = a; a += xch; }
            tot = a;
        }
        __syncthreads();
        int run = carry + wsum[w] + (sc - s);
        if (idx + 0 < NN) rowptr[idx + 0] = run; run += v0;
        if (idx + 1 < NN) rowptr[idx + 1] = run; run += v1;
        if (idx + 2 < NN) rowptr[idx + 2] = run; run += v2;
        if (idx + 3 < NN) rowptr[idx + 3] = run; run += v3;
        carry += tot;
        __syncthreads();
    }
    if (t == 0) rowptr[NN] = carry;
}

__global__ __launch_bounds__(256) void scatter_kernel(const int* __restrict__ src, const int* __restrict__ dst,
                                                      const int* __restrict__ rowptr, int* __restrict__ cur,
                                                      int* __restrict__ csr)
{
    for (int e = blockIdx.x * 256 + threadIdx.x; e < ET; e += gridDim.x * 256) {
        int d, s;
        if (e < EE) { d = dst[e]; s = src[e]; }
        else        { d = e - EE; s = d; }
        int pos = atomicAdd(&cur[d], 1);
        csr[rowptr[d] + pos] = s;
    }
}

// ---------------- GEMM: H = X @ W   (K=128, F=128), W staged in LDS ----------------

__global__ __launch_bounds__(256) void gemm_kernel(const float* __restrict__ X, const float* __restrict__ W,
                                                   float* __restrict__ H, int nrows)
{
    __shared__ float wlds[128 * 128];   // 64 KB
    __shared__ float xlds[64 * 32];     // 8 KB k-chunk staging
    const int t = threadIdx.x;
    // load W (16384 floats = 4096 float4; 16 per thread)
    #pragma unroll
    for (int i = 0; i < 16; i++) {
        int f4 = t + i * 256;
        ((float4*)wlds)[f4] = ((const float4*)W)[f4];
    }
    const int tx = t % 32;  // cols 4*tx .. 4*tx+3
    const int ty = t / 32;  // rows ty + 8*i
    const int ntiles = (nrows + 63) / 64;
    for (int tile = blockIdx.x; tile < ntiles; tile += gridDim.x) {
        const int r0 = tile * 64;
        float acc[8][4] = {};
        for (int kc = 0; kc < 128; kc += 32) {
            __syncthreads();
            // stage X[r0..r0+63][kc..kc+31]: 512 float4, 2 per thread
            #pragma unroll
            for (int j = 0; j < 2; j++) {
                int f4 = t + j * 256;          // 0..511
                int row = f4 >> 3;             // 8 float4 per row
                int kk = (f4 & 7) * 4;
                float4 v = make_float4(0.f, 0.f, 0.f, 0.f);
                if (r0 + row < nrows) v = *(const float4*)&X[(size_t)(r0 + row) * 128 + kc + kk];
                *(float4*)&xlds[row * 32 + kk] = v;
            }
            __syncthreads();
            #pragma unroll
            for (int k = 0; k < 32; k++) {
                float4 w4 = *(float4*)&wlds[(kc + k) * 128 + tx * 4];
                #pragma unroll
                for (int i = 0; i < 8; i++) {
                    float xv = xlds[(ty + 8 * i) * 32 + k];
                    acc[i][0] += xv * w4.x;
                    acc[i][1] += xv * w4.y;
                    acc[i][2] += xv * w4.z;
                    acc[i][3] += xv * w4.w;
                }
            }
        }
        #pragma unroll
        for (int i = 0; i < 8; i++) {
            int r = r0 + ty + 8 * i;
            if (r < nrows)
                *(float4*)&H[(size_t)r * 128 + tx * 4] = make_float4(acc[i][0], acc[i][1], acc[i][2], acc[i][3]);
        }
    }
}

// ---------------- per-node attention logits: al_src/al_dst [N][4] ----------------

__global__ __launch_bounds__(256) void logits_kernel(const float* __restrict__ H,
                                                     const float* __restrict__ att_src,
                                                     const float* __restrict__ att_dst,
                                                     float* __restrict__ alS, float* __restrict__ alD)
{
    const int wid = (blockIdx.x * 256 + threadIdx.x) >> 6;   // node
    const int lane = threadIdx.x & 63;
    if (wid >= NN) return;
    // lane covers channels 2*lane, 2*lane+1  -> head = lane/16
    float2 h2 = ((const float2*)H)[(size_t)wid * 64 + lane];
    float2 a_s = ((const float2*)att_src)[lane];
    float2 a_d = ((const float2*)att_dst)[lane];
    float ps = h2.x * a_s.x + h2.y * a_s.y;
    float pd = h2.x * a_d.x + h2.y * a_d.y;
    #pragma unroll
    for (int off = 8; off; off >>= 1) {
        ps += __shfl_xor(ps, off);
        pd += __shfl_xor(pd, off);
    }
    if ((lane & 15) == 0) {
        int hd = lane >> 4;
        alS[wid * 4 + hd] = ps;
        alD[wid * 4 + hd] = pd;
    }
}

// ---------------- fused segment-softmax + aggregate (one wave per dst node) ----------------

__global__ __launch_bounds__(256) void agg_kernel(const float* __restrict__ H,
                                                  const int* __restrict__ rowptr, const int* __restrict__ csr,
                                                  const float* __restrict__ alS, const float* __restrict__ alD,
                                                  float* __restrict__ OUT, int do_relu)
{
    const int wid = (blockIdx.x * 256 + threadIdx.x) >> 6;   // dst node
    const int lane = threadIdx.x & 63;
    if (wid >= NN) return;
    const int s0 = rowptr[wid], s1 = rowptr[wid + 1];
    const float4 ad = *(const float4*)&alD[wid * 4];

    // phase 1: per-head segment max (lane-parallel over edges)
    float m0 = -1e30f, m1 = -1e30f, m2 = -1e30f, m3 = -1e30f;
    for (int i = s0 + lane; i < s1; i += 64) {
        int s = csr[i];
        float4 as = *(const float4*)&alS[s * 4];
        m0 = fmaxf(m0, leaky(as.x + ad.x));
        m1 = fmaxf(m1, leaky(as.y + ad.y));
        m2 = fmaxf(m2, leaky(as.z + ad.z));
        m3 = fmaxf(m3, leaky(as.w + ad.w));
    }
    #pragma unroll
    for (int off = 32; off; off >>= 1) {
        m0 = fmaxf(m0, __shfl_xor(m0, off));
        m1 = fmaxf(m1, __shfl_xor(m1, off));
        m2 = fmaxf(m2, __shfl_xor(m2, off));
        m3 = fmaxf(m3, __shfl_xor(m3, off));
    }

    // phase 2: edge-sequential accumulate; lane covers channels 2*lane, 2*lane+1 (head lane/16)
    float2 acc = make_float2(0.f, 0.f);
    float den0 = 0.f, den1 = 0.f, den2 = 0.f, den3 = 0.f;
    for (int i = s0; i < s1; i++) {
        int s = csr[i];                                // wave-uniform
        float4 as = *(const float4*)&alS[s * 4];
        float p0 = __expf(leaky(as.x + ad.x) - m0);
        float p1 = __expf(leaky(as.y + ad.y) - m1);
        float p2 = __expf(leaky(as.z + ad.z) - m2);
        float p3 = __expf(leaky(as.w + ad.w) - m3);
        den0 += p0; den1 += p1; den2 += p2; den3 += p3;
        float ph = (lane < 16) ? p0 : (lane < 32) ? p1 : (lane < 48) ? p2 : p3;
        float2 hv = ((const float2*)H)[(size_t)s * 64 + lane];
        acc.x += ph * hv.x;
        acc.y += ph * hv.y;
    }
    float den = (lane < 16) ? den0 : (lane < 32) ? den1 : (lane < 48) ? den2 : den3;
    float inv = 1.f / (den + 1e-16f);
    float o0 = acc.x * inv, o1 = acc.y * inv;
    if (do_relu) { o0 = fmaxf(o0, 0.f); o1 = fmaxf(o1, 0.f); }
    ((float2*)OUT)[(size_t)wid * 64 + lane] = make_float2(o0, o1);
}

// ---------------- launch ----------------

extern "C" void kernel_launch(void* const* d_in, const int* in_sizes, int n_in,
                              void* d_out, int out_size, void* d_ws, size_t ws_size,
                              hipStream_t stream)
{
    const float* x   = (const float*)d_in[0];
    const int*   ei  = (const int*)d_in[1];      // [2][E] int32
    const float* W1  = (const float*)d_in[2];
    const float* as1 = (const float*)d_in[3];
    const float* ad1 = (const float*)d_in[4];
    const float* W2  = (const float*)d_in[5];
    const float* as2 = (const float*)d_in[6];
    const float* ad2 = (const float*)d_in[7];
    const int* srcp = ei;
    const int* dstp = ei + EE;

    char* w = (char*)d_ws;
    float* hA  = (float*)w; w += (size_t)NN * 128 * 4;
    float* hB  = (float*)w; w += (size_t)NN * 128 * 4;
    float* alS = (float*)w; w += (size_t)NN * 4 * 4;
    float* alD = (float*)w; w += (size_t)NN * 4 * 4;
    int* rowptr = (int*)w;  w += (size_t)(NN + 1) * 4;
    int* cnt    = (int*)w;  w += (size_t)NN * 4;
    int* csr    = (int*)w;  w += (size_t)ET * 4;

    // ---- CSR build (reused by both layers) ----
    hipMemsetAsync(cnt, 0, NN * sizeof(int), stream);
    hist_kernel<<<2048, 256, 0, stream>>>(dstp, cnt);
    scan_kernel<<<1, 1024, 0, stream>>>(cnt, rowptr);
    hipMemsetAsync(cnt, 0, NN * sizeof(int), stream);
    scatter_kernel<<<2048, 256, 0, stream>>>(srcp, dstp, rowptr, cnt, csr);

    const int gemm_blocks = (NN + 63) / 64;      // 1563
    const int node_wave_blocks = (NN + 3) / 4;   // 25000

    // ---- layer 1 ----
    gemm_kernel<<<gemm_blocks, 256, 0, stream>>>(x, W1, hA, NN);
    logits_kernel<<<node_wave_blocks, 256, 0, stream>>>(hA, as1, ad1, alS, alD);
    agg_kernel<<<node_wave_blocks, 256, 0, stream>>>(hA, rowptr, csr, alS, alD, hB, 1);

    // ---- layer 2 ----
    gemm_kernel<<<gemm_blocks, 256, 0, stream>>>(hB, W2, hA, NN);
    logits_kernel<<<node_wave_blocks, 256, 0, stream>>>(hA, as2, ad2, alS, alD);
    agg_kernel<<<node_wave_blocks, 256, 0, stream>>>(hA, rowptr, csr, alS, alD, (float*)d_out, 0);
}

// Round 2
// 636.338 us; speedup vs baseline: 1.2810x; 1.2810x over previous
//
#include <hip/hip_runtime.h>

// GAT 2-layer, N=100000, E=1600000 (+N self loops), 128 -> 4x32 -> 4x32
#define NN 100000
#define EE 1600000
#define ET (NN + EE)
#define NPAD 114688   // NN rounded up to 7*16384 for unguarded scan loads

__device__ __forceinline__ float leaky(float x) { return x > 0.f ? x : 0.2f * x; }

// ---------------- CSR build ----------------

__global__ __launch_bounds__(256) void hist_kernel(const int* __restrict__ dst, int* __restrict__ cnt)
{
    for (int e = blockIdx.x * 256 + threadIdx.x; e < ET; e += gridDim.x * 256) {
        int d = (e < EE) ? dst[e] : (e - EE);
        atomicAdd(&cnt[d], 1);
    }
}

// single-block scan, 1024 thr x 16 elem = 16384/iter, 7 iters (cnt padded with zeros)
__global__ __launch_bounds__(1024) void scan_kernel(const int* __restrict__ cnt, int* __restrict__ rowptr)
{
    __shared__ int wsum[16];
    __shared__ int tot;
    const int t = threadIdx.x, lane = t & 63, w = t >> 6;
    int carry = 0;
    for (int base = 0; base < NN; base += 16384) {
        const int idx = base + t * 16;
        int v[16];
        #pragma unroll
        for (int j = 0; j < 4; j++)
            *(int4*)&v[j * 4] = *(const int4*)&cnt[idx + j * 4];
        int s = 0;
        #pragma unroll
        for (int j = 0; j < 16; j++) s += v[j];
        int sc = s;
        #pragma unroll
        for (int off = 1; off < 64; off <<= 1) {
            int u = __shfl_up(sc, off);
            if (lane >= off) sc += u;
        }
        if (lane == 63) wsum[w] = sc;
        __syncthreads();
        if (t == 0) {
            int a = 0;
            for (int i = 0; i < 16; i++) { int xch = wsum[i]; wsum[i] = a; a += xch; }
            tot = a;
        }
        __syncthreads();
        int run = carry + wsum[w] + (sc - s);
        #pragma unroll
        for (int j = 0; j < 16; j++) {
            if (idx + j < NN) rowptr[idx + j] = run;
            run += v[j];
        }
        carry += tot;
        __syncthreads();
    }
    if (t == 0) rowptr[NN] = carry;
}

__global__ __launch_bounds__(256) void scatter_kernel(const int* __restrict__ src, const int* __restrict__ dst,
                                                      const int* __restrict__ rowptr, int* __restrict__ cur,
                                                      int* __restrict__ csr)
{
    for (int e = blockIdx.x * 256 + threadIdx.x; e < ET; e += gridDim.x * 256) {
        int d, s;
        if (e < EE) { d = dst[e]; s = src[e]; }
        else        { d = e - EE; s = d; }
        int pos = atomicAdd(&cur[d], 1);
        csr[rowptr[d] + pos] = s;
    }
}

// ---------------- GEMM: H = X @ W   (K=128, F=128), W staged in LDS ----------------

__global__ __launch_bounds__(256) void gemm_kernel(const float* __restrict__ X, const float* __restrict__ W,
                                                   float* __restrict__ H, int nrows)
{
    __shared__ float wlds[128 * 128];   // 64 KB
    __shared__ float xlds[64 * 32];     // 8 KB k-chunk staging
    const int t = threadIdx.x;
    #pragma unroll
    for (int i = 0; i < 16; i++) {
        int f4 = t + i * 256;
        ((float4*)wlds)[f4] = ((const float4*)W)[f4];
    }
    const int tx = t % 32;  // cols 4*tx .. 4*tx+3
    const int ty = t / 32;  // rows ty + 8*i
    const int ntiles = (nrows + 63) / 64;
    for (int tile = blockIdx.x; tile < ntiles; tile += gridDim.x) {
        const int r0 = tile * 64;
        float acc[8][4] = {};
        for (int kc = 0; kc < 128; kc += 32) {
            __syncthreads();
            #pragma unroll
            for (int j = 0; j < 2; j++) {
                int f4 = t + j * 256;          // 0..511
                int row = f4 >> 3;             // 8 float4 per row
                int kk = (f4 & 7) * 4;
                float4 v = make_float4(0.f, 0.f, 0.f, 0.f);
                if (r0 + row < nrows) v = *(const float4*)&X[(size_t)(r0 + row) * 128 + kc + kk];
                *(float4*)&xlds[row * 32 + kk] = v;
            }
            __syncthreads();
            #pragma unroll
            for (int k = 0; k < 32; k++) {
                float4 w4 = *(float4*)&wlds[(kc + k) * 128 + tx * 4];
                #pragma unroll
                for (int i = 0; i < 8; i++) {
                    float xv = xlds[(ty + 8 * i) * 32 + k];
                    acc[i][0] += xv * w4.x;
                    acc[i][1] += xv * w4.y;
                    acc[i][2] += xv * w4.z;
                    acc[i][3] += xv * w4.w;
                }
            }
        }
        #pragma unroll
        for (int i = 0; i < 8; i++) {
            int r = r0 + ty + 8 * i;
            if (r < nrows)
                *(float4*)&H[(size_t)r * 128 + tx * 4] = make_float4(acc[i][0], acc[i][1], acc[i][2], acc[i][3]);
        }
    }
}

// ---------------- per-node attention logits: al_src/al_dst [N][4] ----------------

__global__ __launch_bounds__(256) void logits_kernel(const float* __restrict__ H,
                                                     const float* __restrict__ att_src,
                                                     const float* __restrict__ att_dst,
                                                     float* __restrict__ alS, float* __restrict__ alD)
{
    const int wid = (blockIdx.x * 256 + threadIdx.x) >> 6;   // node
    const int lane = threadIdx.x & 63;
    if (wid >= NN) return;
    float2 h2 = ((const float2*)H)[(size_t)wid * 64 + lane];
    float2 a_s = ((const float2*)att_src)[lane];
    float2 a_d = ((const float2*)att_dst)[lane];
    float ps = h2.x * a_s.x + h2.y * a_s.y;
    float pd = h2.x * a_d.x + h2.y * a_d.y;
    #pragma unroll
    for (int off = 8; off; off >>= 1) {
        ps += __shfl_xor(ps, off);
        pd += __shfl_xor(pd, off);
    }
    if ((lane & 15) == 0) {
        int hd = lane >> 4;
        alS[wid * 4 + hd] = ps;
        alD[wid * 4 + hd] = pd;
    }
}

// ---------------- fused softmax(no-max) + aggregate, one wave per dst node ----------------
// Phase A (per 64-edge chunk, lane-parallel): p = exp(leaky(alS[src]+alD)), stash p4+src in LDS.
// Phase B (serial over chunk): broadcast p/src from LDS, coalesced 512B H-row gather, fma.
// Denominator accumulates for free in phase B (den += ph per lane, lane's own head).

__global__ __launch_bounds__(256) void agg_kernel(const float* __restrict__ H,
                                                  const int* __restrict__ rowptr, const int* __restrict__ csr,
                                                  const float* __restrict__ alS, const float* __restrict__ alD,
                                                  float* __restrict__ OUT, int do_relu)
{
    __shared__ float pl[4][64 * 4];
    __shared__ int   sl[4][64];
    const int w = threadIdx.x >> 6, lane = threadIdx.x & 63;
    const int wid = (blockIdx.x * 256 + threadIdx.x) >> 6;   // dst node
    if (wid >= NN) return;
    const int s0 = rowptr[wid], s1 = rowptr[wid + 1];
    const float4 ad = *(const float4*)&alD[wid * 4];
    const int hq = lane >> 4;                                 // head of this lane
    const float2* __restrict__ Hl = (const float2*)H + lane;

    float2 acc = make_float2(0.f, 0.f);
    float den = 0.f;
    for (int base = s0; base < s1; base += 64) {
        const int nthis = min(64, s1 - base);
        // phase A: lane-parallel p computation for this chunk
        if (lane < nthis) {
            int s = csr[base + lane];
            float4 as = *(const float4*)&alS[s * 4];
            float4 p;
            p.x = __expf(leaky(as.x + ad.x));
            p.y = __expf(leaky(as.y + ad.y));
            p.z = __expf(leaky(as.z + ad.z));
            p.w = __expf(leaky(as.w + ad.w));
            *(float4*)&pl[w][lane * 4] = p;
            sl[w][lane] = s;
        }
        // same wave wrote LDS; compiler inserts lgkmcnt wait, no barrier needed
        // phase B: serial accumulate with coalesced H-row gather
        for (int k = 0; k < nthis; k++) {
            float ph = pl[w][k * 4 + hq];     // broadcast (4 distinct addrs)
            int s = sl[w][k];                  // broadcast
            float2 hv = Hl[(size_t)s * 64];
            den += ph;
            acc.x += ph * hv.x;
            acc.y += ph * hv.y;
        }
    }
    float inv = 1.f / (den + 1e-16f);
    float o0 = acc.x * inv, o1 = acc.y * inv;
    if (do_relu) { o0 = fmaxf(o0, 0.f); o1 = fmaxf(o1, 0.f); }
    ((float2*)OUT)[(size_t)wid * 64 + lane] = make_float2(o0, o1);
}

// ---------------- launch ----------------

extern "C" void kernel_launch(void* const* d_in, const int* in_sizes, int n_in,
                              void* d_out, int out_size, void* d_ws, size_t ws_size,
                              hipStream_t stream)
{
    const float* x   = (const float*)d_in[0];
    const int*   ei  = (const int*)d_in[1];      // [2][E] int32
    const float* W1  = (const float*)d_in[2];
    const float* as1 = (const float*)d_in[3];
    const float* ad1 = (const float*)d_in[4];
    const float* W2  = (const float*)d_in[5];
    const float* as2 = (const float*)d_in[6];
    const float* ad2 = (const float*)d_in[7];
    const int* srcp = ei;
    const int* dstp = ei + EE;

    char* w = (char*)d_ws;
    float* hA  = (float*)w; w += (size_t)NN * 128 * 4;
    float* hB  = (float*)w; w += (size_t)NN * 128 * 4;
    float* alS = (float*)w; w += (size_t)NN * 4 * 4;
    float* alD = (float*)w; w += (size_t)NN * 4 * 4;
    int* rowptr = (int*)w;  w += (size_t)(NN + 1) * 4;
    int* cnt    = (int*)w;  w += (size_t)NPAD * 4;
    int* csr    = (int*)w;  w += (size_t)ET * 4;

    // ---- CSR build (reused by both layers) ----
    hipMemsetAsync(cnt, 0, NPAD * sizeof(int), stream);
    hist_kernel<<<2048, 256, 0, stream>>>(dstp, cnt);
    scan_kernel<<<1, 1024, 0, stream>>>(cnt, rowptr);
    hipMemsetAsync(cnt, 0, NN * sizeof(int), stream);
    scatter_kernel<<<2048, 256, 0, stream>>>(srcp, dstp, rowptr, cnt, csr);

    const int gemm_blocks = (NN + 63) / 64;      // 1563
    const int node_wave_blocks = (NN + 3) / 4;   // 25000

    // ---- layer 1 ----
    gemm_kernel<<<gemm_blocks, 256, 0, stream>>>(x, W1, hA, NN);
    logits_kernel<<<node_wave_blocks, 256, 0, stream>>>(hA, as1, ad1, alS, alD);
    agg_kernel<<<node_wave_blocks, 256, 0, stream>>>(hA, rowptr, csr, alS, alD, hB, 1);

    // ---- layer 2 ----
    gemm_kernel<<<gemm_blocks, 256, 0, stream>>>(hB, W2, hA, NN);
    logits_kernel<<<node_wave_blocks, 256, 0, stream>>>(hA, as2, ad2, alS, alD);
    agg_kernel<<<node_wave_blocks, 256, 0, stream>>>(hA, rowptr, csr, alS, alD, (float*)d_out, 0);
}

// Round 3
// 503.843 us; speedup vs baseline: 1.6179x; 1.2630x over previous
//
#include <hip/hip_runtime.h>

// GAT 2-layer, N=100000, E=1600000 (+N self loops), 128 -> 4x32 -> 4x32
#define NN 100000
#define EE 1600000
#define ET (NN + EE)
#define NPAD 114688   // NN rounded up to 7*16384 for unguarded scan loads

__device__ __forceinline__ float leaky(float x) { return x > 0.f ? x : 0.2f * x; }

// pack two floats to bf16 pair (RNE), low = a, high = b
__device__ __forceinline__ unsigned int bfpack2(float a, float b)
{
    unsigned int xa = __float_as_uint(a), xb = __float_as_uint(b);
    xa = (xa + 0x7fffu + ((xa >> 16) & 1u)) >> 16;
    xb = (xb + 0x7fffu + ((xb >> 16) & 1u)) & 0xffff0000u;
    return xa | xb;
}

// ---------------- CSR build ----------------

__global__ __launch_bounds__(256) void hist_kernel(const int* __restrict__ dst, int* __restrict__ cnt)
{
    for (int e = blockIdx.x * 256 + threadIdx.x; e < ET; e += gridDim.x * 256) {
        int d = (e < EE) ? dst[e] : (e - EE);
        atomicAdd(&cnt[d], 1);
    }
}

// single-block scan, 1024 thr x 16 elem = 16384/iter, 7 iters (cnt padded with zeros)
__global__ __launch_bounds__(1024) void scan_kernel(const int* __restrict__ cnt, int* __restrict__ rowptr)
{
    __shared__ int wsum[16];
    __shared__ int tot;
    const int t = threadIdx.x, lane = t & 63, w = t >> 6;
    int carry = 0;
    for (int base = 0; base < NN; base += 16384) {
        const int idx = base + t * 16;
        int v[16];
        #pragma unroll
        for (int j = 0; j < 4; j++)
            *(int4*)&v[j * 4] = *(const int4*)&cnt[idx + j * 4];
        int s = 0;
        #pragma unroll
        for (int j = 0; j < 16; j++) s += v[j];
        int sc = s;
        #pragma unroll
        for (int off = 1; off < 64; off <<= 1) {
            int u = __shfl_up(sc, off);
            if (lane >= off) sc += u;
        }
        if (lane == 63) wsum[w] = sc;
        __syncthreads();
        if (t == 0) {
            int a = 0;
            for (int i = 0; i < 16; i++) { int xch = wsum[i]; wsum[i] = a; a += xch; }
            tot = a;
        }
        __syncthreads();
        int run = carry + wsum[w] + (sc - s);
        #pragma unroll
        for (int j = 0; j < 16; j++) {
            if (idx + j < NN) rowptr[idx + j] = run;
            run += v[j];
        }
        carry += tot;
        __syncthreads();
    }
    if (t == 0) rowptr[NN] = carry;
}

__global__ __launch_bounds__(256) void scatter_kernel(const int* __restrict__ src, const int* __restrict__ dst,
                                                      const int* __restrict__ rowptr, int* __restrict__ cur,
                                                      int* __restrict__ csr)
{
    for (int e = blockIdx.x * 256 + threadIdx.x; e < ET; e += gridDim.x * 256) {
        int d, s;
        if (e < EE) { d = dst[e]; s = src[e]; }
        else        { d = e - EE; s = d; }
        int pos = atomicAdd(&cur[d], 1);
        csr[rowptr[d] + pos] = s;
    }
}

// ---------------- GEMM + fused logits: Hbf = bf16(X @ W), al = (X@W)·att  ----------------
// W staged in LDS; epilogue computes per-row per-head logits from fp32 accs (8-lane shfl reduce)
// and writes H only as packed bf16 (halves gather bytes downstream).

__global__ __launch_bounds__(256) void gemm_kernel(const float* __restrict__ X, const float* __restrict__ W,
                                                   const float* __restrict__ att_src, const float* __restrict__ att_dst,
                                                   unsigned int* __restrict__ Hbf,   // [N][64] packed bf16x2
                                                   float* __restrict__ alS, float* __restrict__ alD, int nrows)
{
    __shared__ float wlds[128 * 128];   // 64 KB
    __shared__ float xlds[64 * 32];     // 8 KB k-chunk staging
    const int t = threadIdx.x;
    #pragma unroll
    for (int i = 0; i < 16; i++) {
        int f4 = t + i * 256;
        ((float4*)wlds)[f4] = ((const float4*)W)[f4];
    }
    const int tx = t % 32;  // cols 4*tx .. 4*tx+3
    const int ty = t / 32;  // rows ty + 8*i
    const int head = tx >> 3;
    const float4 asv = *(const float4*)&att_src[tx * 4];
    const float4 adv = *(const float4*)&att_dst[tx * 4];
    const int ntiles = (nrows + 63) / 64;
    for (int tile = blockIdx.x; tile < ntiles; tile += gridDim.x) {
        const int r0 = tile * 64;
        float acc[8][4] = {};
        for (int kc = 0; kc < 128; kc += 32) {
            __syncthreads();
            #pragma unroll
            for (int j = 0; j < 2; j++) {
                int f4 = t + j * 256;          // 0..511
                int row = f4 >> 3;             // 8 float4 per row
                int kk = (f4 & 7) * 4;
                float4 v = make_float4(0.f, 0.f, 0.f, 0.f);
                if (r0 + row < nrows) v = *(const float4*)&X[(size_t)(r0 + row) * 128 + kc + kk];
                *(float4*)&xlds[row * 32 + kk] = v;
            }
            __syncthreads();
            #pragma unroll
            for (int k = 0; k < 32; k++) {
                float4 w4 = *(float4*)&wlds[(kc + k) * 128 + tx * 4];
                #pragma unroll
                for (int i = 0; i < 8; i++) {
                    float xv = xlds[(ty + 8 * i) * 32 + k];
                    acc[i][0] += xv * w4.x;
                    acc[i][1] += xv * w4.y;
                    acc[i][2] += xv * w4.z;
                    acc[i][3] += xv * w4.w;
                }
            }
        }
        #pragma unroll
        for (int i = 0; i < 8; i++) {
            int r = r0 + ty + 8 * i;
            if (r < nrows) {
                uint2 wv;
                wv.x = bfpack2(acc[i][0], acc[i][1]);
                wv.y = bfpack2(acc[i][2], acc[i][3]);
                *(uint2*)&Hbf[(size_t)r * 64 + tx * 2] = wv;
                float ps = acc[i][0] * asv.x + acc[i][1] * asv.y + acc[i][2] * asv.z + acc[i][3] * asv.w;
                float pd = acc[i][0] * adv.x + acc[i][1] * adv.y + acc[i][2] * adv.z + acc[i][3] * adv.w;
                // reduce over the 8 lanes covering this head's 32 channels (same half-wave)
                #pragma unroll
                for (int off = 1; off <= 4; off <<= 1) {
                    ps += __shfl_xor(ps, off);
                    pd += __shfl_xor(pd, off);
                }
                if ((tx & 7) == 0) {
                    alS[r * 4 + head] = ps;
                    alD[r * 4 + head] = pd;
                }
            }
        }
    }
}

// ---------------- fused softmax(no-max) + aggregate, one wave per dst node ----------------
// Phase A (per 64-edge chunk, lane-parallel): p = exp(leaky(alS[src]+alD)), stash p4+src in LDS.
// Phase B (serial over chunk): broadcast p/src from LDS, coalesced 256B bf16 H-row gather, fma.

__global__ __launch_bounds__(256) void agg_kernel(const unsigned int* __restrict__ Hbf,
                                                  const int* __restrict__ rowptr, const int* __restrict__ csr,
                                                  const float* __restrict__ alS, const float* __restrict__ alD,
                                                  float* __restrict__ OUT, int do_relu)
{
    __shared__ float pl[4][64 * 4];
    __shared__ int   sl[4][64];
    const int w = threadIdx.x >> 6, lane = threadIdx.x & 63;
    const int wid = (blockIdx.x * 256 + threadIdx.x) >> 6;   // dst node
    if (wid >= NN) return;
    const int s0 = rowptr[wid], s1 = rowptr[wid + 1];
    const float4 ad = *(const float4*)&alD[wid * 4];
    const int hq = lane >> 4;                                 // head of this lane
    const unsigned int* __restrict__ Hl = Hbf + lane;         // lane's 2 channels (4B)

    float2 acc = make_float2(0.f, 0.f);
    float den = 0.f;
    for (int base = s0; base < s1; base += 64) {
        const int nthis = min(64, s1 - base);
        // phase A: lane-parallel p computation for this chunk
        if (lane < nthis) {
            int s = csr[base + lane];
            float4 as = *(const float4*)&alS[s * 4];
            float4 p;
            p.x = __expf(leaky(as.x + ad.x));
            p.y = __expf(leaky(as.y + ad.y));
            p.z = __expf(leaky(as.z + ad.z));
            p.w = __expf(leaky(as.w + ad.w));
            *(float4*)&pl[w][lane * 4] = p;
            sl[w][lane] = s;
        }
        // same-wave LDS write/read; compiler inserts lgkmcnt wait, no barrier needed
        int k = 0;
        for (; k + 2 <= nthis; k += 2) {
            float pa = pl[w][k * 4 + hq];
            float pb = pl[w][k * 4 + 4 + hq];
            int sa = sl[w][k];
            int sb = sl[w][k + 1];
            unsigned int ua = Hl[(size_t)sa * 64];
            unsigned int ub = Hl[(size_t)sb * 64];
            den += pa + pb;
            acc.x += pa * __uint_as_float(ua << 16);
            acc.y += pa * __uint_as_float(ua & 0xffff0000u);
            acc.x += pb * __uint_as_float(ub << 16);
            acc.y += pb * __uint_as_float(ub & 0xffff0000u);
        }
        if (k < nthis) {
            float pa = pl[w][k * 4 + hq];
            int sa = sl[w][k];
            unsigned int ua = Hl[(size_t)sa * 64];
            den += pa;
            acc.x += pa * __uint_as_float(ua << 16);
            acc.y += pa * __uint_as_float(ua & 0xffff0000u);
        }
    }
    float inv = 1.f / (den + 1e-16f);
    float o0 = acc.x * inv, o1 = acc.y * inv;
    if (do_relu) { o0 = fmaxf(o0, 0.f); o1 = fmaxf(o1, 0.f); }
    ((float2*)OUT)[(size_t)wid * 64 + lane] = make_float2(o0, o1);
}

// ---------------- launch ----------------

extern "C" void kernel_launch(void* const* d_in, const int* in_sizes, int n_in,
                              void* d_out, int out_size, void* d_ws, size_t ws_size,
                              hipStream_t stream)
{
    const float* x   = (const float*)d_in[0];
    const int*   ei  = (const int*)d_in[1];      // [2][E] int32
    const float* W1  = (const float*)d_in[2];
    const float* as1 = (const float*)d_in[3];
    const float* ad1 = (const float*)d_in[4];
    const float* W2  = (const float*)d_in[5];
    const float* as2 = (const float*)d_in[6];
    const float* ad2 = (const float*)d_in[7];
    const int* srcp = ei;
    const int* dstp = ei + EE;

    char* w = (char*)d_ws;
    float* hB  = (float*)w;         w += (size_t)NN * 128 * 4;   // layer-1 output (fp32)
    unsigned int* Hbf = (unsigned int*)w; w += (size_t)NN * 64 * 4; // packed bf16 H (reused both layers)
    float* alS = (float*)w; w += (size_t)NN * 4 * 4;
    float* alD = (float*)w; w += (size_t)NN * 4 * 4;
    int* rowptr = (int*)w;  w += (size_t)(NN + 1) * 4;
    int* cnt    = (int*)w;  w += (size_t)NPAD * 4;
    int* csr    = (int*)w;  w += (size_t)ET * 4;

    // ---- CSR build (reused by both layers) ----
    hipMemsetAsync(cnt, 0, NPAD * sizeof(int), stream);
    hist_kernel<<<2048, 256, 0, stream>>>(dstp, cnt);
    scan_kernel<<<1, 1024, 0, stream>>>(cnt, rowptr);
    hipMemsetAsync(cnt, 0, NN * sizeof(int), stream);
    scatter_kernel<<<2048, 256, 0, stream>>>(srcp, dstp, rowptr, cnt, csr);

    const int gemm_blocks = (NN + 63) / 64;      // 1563
    const int node_wave_blocks = (NN + 3) / 4;   // 25000

    // ---- layer 1 ----
    gemm_kernel<<<gemm_blocks, 256, 0, stream>>>(x, W1, as1, ad1, Hbf, alS, alD, NN);
    agg_kernel<<<node_wave_blocks, 256, 0, stream>>>(Hbf, rowptr, csr, alS, alD, hB, 1);

    // ---- layer 2 ----
    gemm_kernel<<<gemm_blocks, 256, 0, stream>>>(hB, W2, as2, ad2, Hbf, alS, alD, NN);
    agg_kernel<<<node_wave_blocks, 256, 0, stream>>>(Hbf, rowptr, csr, alS, alD, (float*)d_out, 0);
}